// Round 6
// baseline (469.939 us; speedup 1.0000x reference)
//
#include <hip/hip_runtime.h>
#include <math.h>

#define Bb 8
#define Nn 2048
#define Mm 2048
#define Cc 512

typedef __attribute__((ext_vector_type(8))) _Float16 hfrag;  // 8 f16 = 4 VGPRs
typedef __attribute__((ext_vector_type(4))) float f4;        // MFMA acc
typedef __attribute__((ext_vector_type(4))) _Float16 h4;

__device__ __forceinline__ void gld16(const void* g, void* l) {
    __builtin_amdgcn_global_load_lds(
        (const __attribute__((address_space(1))) void*)g,
        (__attribute__((address_space(3))) void*)l, 16, 0, 0);
}

// counted vmcnt wait + scheduler fence (rule #18) -- used by gemm_mfma
template<int N> __device__ __forceinline__ void wait_vmcnt() {
    if constexpr (N == 0)      asm volatile("s_waitcnt vmcnt(0)" ::: "memory");
    else if constexpr (N == 3) asm volatile("s_waitcnt vmcnt(3)" ::: "memory");
    else if constexpr (N == 4) asm volatile("s_waitcnt vmcnt(4)" ::: "memory");
    __builtin_amdgcn_sched_barrier(0);
}

// ---------------------------------------------------------------------------
// attn_fused: replaces EPI0 (score+softmax p1) + combine + EPI2 (PV+gate).
// Per block: one (bz, 64-row n-tile). 256 threads, 4 waves. Grid 256 = 1/CU.
// Loop mt over 8 m-tiles of 256:
//   S-phase: S^T[n64][m256] = enc x dec over k=C (BK=32 dbuf, proven r2
//            structure: swizzled gld_lds staging + swizzled ds_read).
//            Wave wv owns m-slice wv*64; all waves share the n 64.
//   A-phase: mask-mult (f4 global, j-pipelined); per-n wave-local max ->
//            MXS; barrier.
//   B-phase: m_new = max(m_run, all-wave max) [m_run init 0 == implicit
//            zero entries in the softmax max]; alpha = exp(m_old-m_new);
//            P = exp(s_masked - m_new), masked->0 exactly as old EPI0
//            (s==0 test AFTER mask-mult); l-partials -> LSS; P (f16) ->
//            PL[n][m] XOR-swizzled (write 8B units, read 16B units, XOR on
//            byte bits 4-6 keyed by n&7 -> involution, alignment-safe,
//            uniform banks both sides, enumerated); barrier.
//   C-phase: l_run = l_run*alpha + sum(LSS); o *= alpha (alpha is lane-
//            local per j because score and PV share the n<->lane map).
//   P-phase: o += vT x P over k=m256 (BK=32 dbuf; A=vT staged exactly like
//            old EPI2; B-frags straight from PL). Wave wv owns c-slice 128.
// Finalize: g[n][c] = dec_h[n][c] * (1 + tanh(o/l)), h4 stores.
// Correctness of softmax shift: l uses the same M for every term, so any
// M >= rowmax gives the exact softmax; M = max(0, scores) == reference's
// max since masked entries are 0-valued participants.  LDS 138KB, 1 blk/CU.
// ---------------------------------------------------------------------------
__global__ __launch_bounds__(256, 1) void attn_fused(
    const _Float16* __restrict__ Eg,   // enc_h [8][2048][512]
    const _Float16* __restrict__ Qg,   // dec_h [8][2048][512]
    const _Float16* __restrict__ Vg,   // vT    [8][512][2048]
    const float*    __restrict__ Mg,   // mask  [8][2048][2048] fp32
    _Float16* __restrict__ Gg)         // g out [8][2048][512]
{
    __shared__ _Float16 EA[2][256 * 32];   // enc panels   32 KB
    __shared__ _Float16 QB[2][64 * 32];    // dec panels    8 KB
    __shared__ _Float16 VA[2][512 * 32];   // vT panels    64 KB
    __shared__ _Float16 PL[64 * 256];      // P tile       32 KB (swizzled)
    __shared__ float MXS[4][64];
    __shared__ float LSS[4][64];

    const int id = blockIdx.x;
    const int bz = id & 7;                 // batch -> XCD
    const int n0 = (id >> 3) * 64;

    const _Float16* E0 = Eg + (size_t)bz * ((size_t)Mm * Cc);
    const _Float16* Q0 = Qg + (size_t)bz * ((size_t)Nn * Cc) + (size_t)n0 * Cc;
    const _Float16* V0 = Vg + (size_t)bz * ((size_t)Cc * Mm);
    const float*    M0 = Mg + (size_t)bz * ((size_t)Nn * Mm);

    const int tid = threadIdx.x;
    const int wv = tid >> 6, ln = tid & 63;
    const int lcol = ln & 15, quad = ln >> 4;
    const int soff = (quad ^ ((lcol >> 1) & 3)) * 8;
    char* PLb = (char*)PL;

    f4 o[8][4];                            // c = wv*128+i*16+quad*4+r, n = j*16+lcol
    const f4 z4 = {0.f, 0.f, 0.f, 0.f};
    #pragma unroll
    for (int i = 0; i < 8; ++i)
        #pragma unroll
        for (int j = 0; j < 4; ++j) o[i][j] = z4;
    float mrun[4] = {0.f, 0.f, 0.f, 0.f};  // init 0 = implicit masked zeros
    float lrun[4] = {0.f, 0.f, 0.f, 0.f};

    for (int mt = 0; mt < 8; ++mt) {
        const int m0 = mt * 256;

        // ---- S-phase: score GEMM ---------------------------------------
        f4 sa[4][4];
        #pragma unroll
        for (int i = 0; i < 4; ++i)
            #pragma unroll
            for (int j = 0; j < 4; ++j) sa[i][j] = z4;

        auto SSTAGE = [&](int k0, int p) {
            #pragma unroll
            for (int q = 0; q < 5; ++q) {
                const int c = q * 256 + tid;
                if (c < 1024) {
                    const int r = c >> 2, gsw = (c & 3) ^ ((c >> 3) & 3);
                    gld16(E0 + (size_t)(m0 + r) * Cc + k0 + gsw * 8, &EA[p][c * 8]);
                } else {
                    const int cb = c - 1024;
                    const int r = cb >> 2, gsw = (cb & 3) ^ ((cb >> 3) & 3);
                    gld16(Q0 + (size_t)r * Cc + k0 + gsw * 8, &QB[p][cb * 8]);
                }
            }
        };
        // early mask prefetch for j=0 (hides first-column HBM latency)
        const float* Mkb = M0 + (size_t)(n0 + lcol) * Mm + m0 + wv * 64 + quad * 4;
        f4 mk[4], mkN[4];
        #pragma unroll
        for (int i = 0; i < 4; ++i) mk[i] = *(const f4*)(Mkb + i * 16);

        SSTAGE(0, 0);
        __syncthreads();
        for (int t = 0; t < 16; ++t) {
            const int p = t & 1;
            if (t + 1 < 16) SSTAGE((t + 1) * 32, p ^ 1);
            hfrag af[4], bf[4];
            #pragma unroll
            for (int i = 0; i < 4; ++i)
                af[i] = *(const hfrag*)&EA[p][(wv * 64 + i * 16 + lcol) * 32 + soff];
            #pragma unroll
            for (int j = 0; j < 4; ++j)
                bf[j] = *(const hfrag*)&QB[p][(j * 16 + lcol) * 32 + soff];
            #pragma unroll
            for (int i = 0; i < 4; ++i)
                #pragma unroll
                for (int j = 0; j < 4; ++j)
                    sa[i][j] = __builtin_amdgcn_mfma_f32_16x16x32_f16(af[i], bf[j], sa[i][j], 0, 0, 0);
            if (t + 1 < 16) __syncthreads();
        }

        // ---- A-phase: mask + wave-local max ----------------------------
        #pragma unroll
        for (int j = 0; j < 4; ++j) {
            if (j < 3) {
                #pragma unroll
                for (int i = 0; i < 4; ++i)
                    mkN[i] = *(const f4*)(Mkb + (size_t)(j + 1) * 16 * Mm + i * 16);
            }
            #pragma unroll
            for (int i = 0; i < 4; ++i)
                #pragma unroll
                for (int r = 0; r < 4; ++r) sa[i][j][r] *= mk[i][r];
            float mx = 0.f;
            #pragma unroll
            for (int i = 0; i < 4; ++i)
                #pragma unroll
                for (int r = 0; r < 4; ++r) mx = fmaxf(mx, sa[i][j][r]);
            mx = fmaxf(mx, __shfl_xor(mx, 16, 64));
            mx = fmaxf(mx, __shfl_xor(mx, 32, 64));
            if (quad == 0) MXS[wv][j * 16 + lcol] = mx;
            if (j < 3) {
                #pragma unroll
                for (int i = 0; i < 4; ++i) mk[i] = mkN[i];
            }
        }
        __syncthreads();                                   // S1

        // ---- B-phase: m_new/alpha, P -> PL, l-partials -----------------
        float al[4], mnew[4];
        #pragma unroll
        for (int j = 0; j < 4; ++j) {
            const int n = j * 16 + lcol;
            float mm = mrun[j];
            mm = fmaxf(mm, MXS[0][n]); mm = fmaxf(mm, MXS[1][n]);
            mm = fmaxf(mm, MXS[2][n]); mm = fmaxf(mm, MXS[3][n]);
            al[j] = __expf(mrun[j] - mm);
            mrun[j] = mm; mnew[j] = mm;
        }
        #pragma unroll
        for (int j = 0; j < 4; ++j) {
            const int n = j * 16 + lcol;
            float lp = 0.f;
            #pragma unroll
            for (int i = 0; i < 4; ++i) {
                h4 pv;
                #pragma unroll
                for (int r = 0; r < 4; ++r) {
                    const float s = sa[i][j][r];
                    const float e = __expf(s - mnew[j]);
                    lp += e;
                    pv[r] = (s == 0.f) ? (_Float16)0.f : (_Float16)e;
                }
                *(h4*)(PLb + n * 512 +
                       (((wv << 7) + (i << 5) + (quad << 3)) ^ ((n & 7) << 4))) = pv;
            }
            lp += __shfl_xor(lp, 16, 64);
            lp += __shfl_xor(lp, 32, 64);
            if (quad == 0) LSS[wv][n] = lp;
        }
        __syncthreads();                                   // S2

        // ---- C-phase: l_run update + o rescale -------------------------
        #pragma unroll
        for (int j = 0; j < 4; ++j) {
            const int n = j * 16 + lcol;
            const float ls = LSS[0][n] + LSS[1][n] + LSS[2][n] + LSS[3][n];
            lrun[j] = lrun[j] * al[j] + ls;
            #pragma unroll
            for (int i = 0; i < 8; ++i)
                #pragma unroll
                for (int r = 0; r < 4; ++r) o[i][j][r] *= al[j];
        }

        // ---- P-phase: PV GEMM ------------------------------------------
        auto VSTAGE = [&](int k0, int p) {
            #pragma unroll
            for (int q = 0; q < 8; ++q) {
                const int c = q * 256 + tid;
                const int r = c >> 2, gsw = (c & 3) ^ ((c >> 3) & 3);
                gld16(V0 + (size_t)r * Mm + m0 + k0 + gsw * 8, &VA[p][c * 8]);
            }
        };
        VSTAGE(0, 0);
        __syncthreads();                                   // S3
        for (int t = 0; t < 8; ++t) {
            const int p = t & 1;
            if (t + 1 < 8) VSTAGE((t + 1) * 32, p ^ 1);
            hfrag va[8], pb[4];
            #pragma unroll
            for (int i = 0; i < 8; ++i)
                va[i] = *(const hfrag*)&VA[p][(wv * 128 + i * 16 + lcol) * 32 + soff];
            #pragma unroll
            for (int j = 0; j < 4; ++j) {
                const int n = j * 16 + lcol;
                pb[j] = *(const hfrag*)(PLb + n * 512 +
                        (((t << 6) + (quad << 4)) ^ ((n & 7) << 4)));
            }
            #pragma unroll
            for (int i = 0; i < 8; ++i)
                #pragma unroll
                for (int j = 0; j < 4; ++j)
                    o[i][j] = __builtin_amdgcn_mfma_f32_16x16x32_f16(va[i], pb[j], o[i][j], 0, 0, 0);
            if (t + 1 < 8) __syncthreads();
        }
        __syncthreads();                                   // S4: PL reusable
    }

    // ---- finalize: g = dec_h * (1 + tanh(o/l)) -------------------------
    const _Float16* Db = Qg + (size_t)bz * ((size_t)Nn * Cc);
    _Float16* Gb = Gg + (size_t)bz * ((size_t)Nn * Cc);
    #pragma unroll
    for (int j = 0; j < 4; ++j) {
        const int n = n0 + j * 16 + lcol;
        const float inv = 1.f / lrun[j];
        #pragma unroll
        for (int i = 0; i < 8; ++i) {
            const int c0 = wv * 128 + i * 16 + quad * 4;
            const h4 dv = *(const h4*)(Db + (size_t)n * Cc + c0);
            h4 gv;
            #pragma unroll
            for (int r = 0; r < 4; ++r) {
                const float a = o[i][j][r] * inv;
                const float th = 1.f - 2.f / (__expf(2.f * a) + 1.f);
                gv[r] = (_Float16)((float)dv[r] * (1.f + th));
            }
            *(h4*)(Gb + (size_t)n * Cc + c0) = gv;
        }
    }
}

// ---------------------------------------------------------------------------
// MFMA GEMM (f16 in, fp32 acc), 128xBN tile, BK=32, ring-of-3 LDS buffers,
// counted vmcnt + raw s_barrier (r3 structure, verified). EPI 1/3/4 only.
// ---------------------------------------------------------------------------
template<int EPI, int BN, int SWZ>
__global__ __launch_bounds__(256) void gemm_mfma(
    const _Float16* __restrict__ Ah, long sA, int lda,
    const _Float16* __restrict__ Bh, long sB, int ldb,
    const float* __restrict__ aux, long sAux, int ldaux,     // f32 bias
    void* __restrict__ Cout, long sC, int ldc, int K, int GX)
{
    constexpr int NI  = (BN == 128) ? 4 : 2;
    constexpr int ASL = 512;
    constexpr int BSL = BN * 4;
    constexpr int NQ  = (ASL + BSL) / 256;

    __shared__ _Float16 As[3][128 * 32];
    __shared__ _Float16 Bs[3][BN * 32];

    int bx, by, bz;
    if (SWZ == 1) {
        const int id = blockIdx.x;
        bz = id & 7; bx = (id >> 3) % GX; by = (id >> 3) / GX;
    } else if (SWZ == 2) {
        const int id = blockIdx.x;
        bz = 0; bx = (id >> 3) % GX; by = (id & 7) + 8 * ((id >> 3) / GX);
    } else {
        bx = blockIdx.x; by = blockIdx.y; bz = 0;
    }

    const _Float16* A0 = Ah + (size_t)bz * sA;
    const _Float16* B0 = Bh + (size_t)bz * sB;

    const int tid  = threadIdx.x;
    const int wv   = tid >> 6;
    const int ln   = tid & 63;
    const int wx   = (BN == 128) ? (wv & 1) : 0;
    const int wy   = (BN == 128) ? (wv >> 1) : wv;
    const int lcol = ln & 15, quad = ln >> 4;
    const int row0w = wy * (NI * 16);
    const int col0w = wx * 64;

    const int rowBase = by * 128;
    const int colBase = bx * BN;
    const int soff = (quad ^ ((lcol >> 1) & 3)) * 8;

    f4 acc[NI][4];
    const f4 z4 = {0.f, 0.f, 0.f, 0.f};
    #pragma unroll
    for (int i = 0; i < NI; ++i)
        #pragma unroll
        for (int j = 0; j < 4; ++j) acc[i][j] = z4;

    auto STAGE = [&](int k0, int p) {
        #pragma unroll
        for (int q = 0; q < NQ; ++q) {
            const int c = q * 256 + wv * 64 + ln;
            if (c < ASL) {
                const int r = c >> 2;
                const int g = (c & 3) ^ ((c >> 3) & 3);
                gld16(A0 + (size_t)(rowBase + r) * lda + k0 + g * 8, &As[p][c * 8]);
            } else {
                const int cb = c - ASL;
                const int r  = cb >> 2;
                const int g  = (cb & 3) ^ ((cb >> 3) & 3);
                gld16(B0 + (size_t)(colBase + r) * ldb + k0 + g * 8, &Bs[p][cb * 8]);
            }
        }
    };

    const int NT = K >> 5;
    STAGE(0, 0);
    STAGE(32, 1);
    wait_vmcnt<NQ>();
    __builtin_amdgcn_s_barrier();

    int p = 0, pn2 = 2;
    for (int t = 0; t < NT; ++t) {
        if (t + 2 < NT) STAGE((t + 2) * 32, pn2);

        hfrag af[NI], bf_[4];
        #pragma unroll
        for (int i = 0; i < NI; ++i)
            af[i]  = *(const hfrag*)&As[p][(row0w + i * 16 + lcol) * 32 + soff];
        #pragma unroll
        for (int j = 0; j < 4; ++j)
            bf_[j] = *(const hfrag*)&Bs[p][(col0w + j * 16 + lcol) * 32 + soff];

        #pragma unroll
        for (int i = 0; i < NI; ++i)
            #pragma unroll
            for (int j = 0; j < 4; ++j)
                acc[i][j] = __builtin_amdgcn_mfma_f32_16x16x32_f16(af[i], bf_[j], acc[i][j], 0, 0, 0);

        if (t + 1 < NT) {
            if (t + 2 < NT) wait_vmcnt<NQ>();
            else            wait_vmcnt<0>();
            __builtin_amdgcn_s_barrier();
        }
        p   = (p   == 2) ? 0 : p + 1;
        pn2 = (pn2 == 2) ? 0 : pn2 + 1;
    }

    const int crow0 = rowBase + row0w + quad * 4;
    const int ccol0 = colBase + col0w + lcol;

    if (EPI == 1) {            // v^T: vT[b][c][m] = acc + bias[c], h4
        _Float16* C = (_Float16*)Cout;
        #pragma unroll
        for (int j = 0; j < 4; ++j) {
            const int col = ccol0 + j * 16;
            const float bi = aux[col];
            #pragma unroll
            for (int i = 0; i < NI; ++i) {
                const int rowb = crow0 + i * 16;
                const int bb = rowb >> 11, ml = rowb & 2047;
                h4 st;
                #pragma unroll
                for (int r = 0; r < 4; ++r) st[r] = (_Float16)(acc[i][j][r] + bi);
                *(h4*)(C + (size_t)bb * ((size_t)Cc * Mm) + (size_t)col * Mm + ml) = st;
            }
        }
    } else if (EPI == 3) {     // fc1: h[n][c2] = relu(acc + b1[c2]), h4
        _Float16* C = (_Float16*)Cout;
        #pragma unroll
        for (int i = 0; i < NI; ++i) {
            const int c0 = crow0 + i * 16;
            const f4 bi = *(const f4*)(aux + c0);
            #pragma unroll
            for (int j = 0; j < 4; ++j) {
                const int n = ccol0 + j * 16;
                h4 hv;
                #pragma unroll
                for (int r = 0; r < 4; ++r)
                    hv[r] = (_Float16)fmaxf(acc[i][j][r] + bi[r], 0.f);
                *(h4*)(C + (size_t)n * ldc + c0) = hv;
            }
        }
    } else {                   // fc2: out[n][c3] = acc + b2[c3], f4 stores
        float* C = (float*)Cout;
        #pragma unroll
        for (int i = 0; i < NI; ++i) {
            const int c0 = crow0 + i * 16;
            const f4 bi = *(const f4*)(aux + c0);
            #pragma unroll
            for (int j = 0; j < 4; ++j) {
                const int n = ccol0 + j * 16;
                f4 ov;
                #pragma unroll
                for (int r = 0; r < 4; ++r) ov[r] = acc[i][j][r] + bi[r];
                *(f4*)(C + (size_t)n * ldc + c0) = ov;
            }
        }
    }
}

// fp32 -> f16, vectorized x4. grid*256*4 == element count.
__global__ __launch_bounds__(256) void sconv(const float* __restrict__ x,
                                             _Float16* __restrict__ o)
{
    const size_t i = (size_t)blockIdx.x * 256 + threadIdx.x;
    f4 v = ((const f4*)x)[i];
    h4 hh;
    #pragma unroll
    for (int k = 0; k < 4; ++k) hh[k] = (_Float16)v[k];
    ((h4*)o)[i] = hh;
}

// W [512,512] fp32 -> Wt [512,512] f16 transposed (Wt[n][k] = W[k][n]).
__global__ __launch_bounds__(256) void wconv(const float* s0, const float* s1, const float* s2,
                                             _Float16* d0, _Float16* d1, _Float16* d2)
{
    const float* Sm = blockIdx.z == 0 ? s0 : blockIdx.z == 1 ? s1 : s2;
    _Float16* D = blockIdx.z == 0 ? d0 : blockIdx.z == 1 ? d1 : d2;
    __shared__ float t[32][33];
    const int x = threadIdx.x & 31, y = threadIdx.x >> 5;
    const int gx = blockIdx.x * 32, gy = blockIdx.y * 32;
    #pragma unroll
    for (int yy = y; yy < 32; yy += 8)
        t[yy][x] = Sm[(size_t)(gy + yy) * 512 + gx + x];
    __syncthreads();
    #pragma unroll
    for (int yy = y; yy < 32; yy += 8)
        D[(size_t)(gx + yy) * 512 + gy + x] = (_Float16)t[x][yy];
}

// ---------------------------------------------------------------------------
// ws layout:
//   dec_h[0x4600000, 0x5600000)  f16 [bn][c]
//   Wvt/W1t/W2t [0x5600000, +3*512KB)
//   vT   [0x5800000, 0x6800000)  f16 [b][c][m]
//   g    [0x6800000, 0x7800000)  f16 [bn][c]
//   h    [0x7800000, 0x8800000)  f16 [bn][c2]
//   enc_h in d_out (dead before fc2 writes).
// ---------------------------------------------------------------------------
extern "C" void kernel_launch(void* const* d_in, const int* in_sizes, int n_in,
                              void* d_out, int out_size, void* d_ws, size_t ws_size,
                              hipStream_t stream)
{
    const float* dec   = (const float*)d_in[0];
    const float* enc   = (const float*)d_in[1];
    const float* trans = (const float*)d_in[2];
    const float* Wv = (const float*)d_in[3];
    const float* bv = (const float*)d_in[4];
    const float* W1 = (const float*)d_in[5];
    const float* b1 = (const float*)d_in[6];
    const float* W2 = (const float*)d_in[7];
    const float* b2 = (const float*)d_in[8];

    char* ws = (char*)d_ws;
    _Float16* dec_h = (_Float16*)(ws + 0x4600000);
    _Float16* Wvt   = (_Float16*)(ws + 0x5600000);
    _Float16* W1t   = Wvt + 262144;
    _Float16* W2t   = Wvt + 524288;
    _Float16* vT    = (_Float16*)(ws + 0x5800000);
    _Float16* g     = (_Float16*)(ws + 0x6800000);
    _Float16* h     = (_Float16*)(ws + 0x7800000);
    _Float16* enc_h = (_Float16*)d_out;

    sconv<<<dim3(8192), 256, 0, stream>>>(dec, dec_h);
    sconv<<<dim3(8192), 256, 0, stream>>>(enc, enc_h);
    wconv<<<dim3(16, 16, 3), 256, 0, stream>>>(Wv, W1, W2, Wvt, W1t, W2t);

    // v^T = (enc @ Wv + bv)^T  [b][c][m]   [SWZ2, GX=8]
    gemm_mfma<1, 64, 2><<<dim3(1024), 256, 0, stream>>>(
        enc_h, 0, 512, Wvt, 0, 512, bv, 0, 0,
        vT, 0, 0, 512, 8);

    // fused: score + masked-softmax + PV + gate -> g
    attn_fused<<<dim3(256), 256, 0, stream>>>(enc_h, dec_h, vT, trans, g);

    // h[n][c2] = relu(g @ W1 + b1):  A=W1^T (rows=c2), B=g (cols=n)
    gemm_mfma<3, 64, 0><<<dim3(256, 4), 256, 0, stream>>>(
        W1t, 0, 512, g, 0, 512, b1, 0, 0,
        h, 0, 512, 512, 0);

    // out[n][c3] = h @ W2 + b2:  A=W2^T (rows=c3), B=h (cols=n), fp32
    gemm_mfma<4, 64, 0><<<dim3(256, 4), 256, 0, stream>>>(
        W2t, 0, 512, h, 0, 512, b2, 0, 0,
        d_out, 0, 512, 512, 0);
}